// Round 16
// baseline (172.954 us; speedup 1.0000x reference)
//
#include <hip/hip_runtime.h>
#include <hip/hip_bf16.h>
#include <math.h>

#define PI_F 3.14159265358979323846f

typedef float f32x4 __attribute__((ext_vector_type(4)));

// ---------------------------------------------------------------------------
// Kernel 1: build the fixed 64x64 complex unitary U. One block per INPUT
// basis state b. K-MAJOR layout for the wave-cooperative gemv: row k = lane
// holds 64 (re,im) pairs contiguously: Umat[(k*64 + j)*2 + {0,1}] = U[k][j].
// ---------------------------------------------------------------------------
__global__ __launch_bounds__(64) void build_u(const float* __restrict__ qw,
                                              float* __restrict__ Umat) {
    const int l = threadIdx.x;   // amplitude index k (0..63)
    const int b = blockIdx.x;    // input basis state j (0..63)

    float ar = (l == b) ? 1.0f : 0.0f;
    float ai = 0.0f;

    #pragma unroll
    for (int i = 0; i < 6; ++i) {
        const int mask = 1 << (5 - i);
        float th = 0.5f * qw[0 * 6 + i];
        float c = cosf(th), sn = sinf(th);
        float pr = __shfl_xor(ar, mask);
        float pi = __shfl_xor(ai, mask);
        float nr = c * ar + sn * pi;
        float ni = c * ai - sn * pr;
        ar = nr; ai = ni;
        th = 0.5f * qw[1 * 6 + i];
        c = cosf(th); sn = sinf(th);
        float zn = (l & mask) ? 1.0f : -1.0f;
        nr = c * ar - zn * sn * ai;
        ni = c * ai + zn * sn * ar;
        ar = nr; ai = ni;
    }

    #pragma unroll
    for (int i = 0; i < 6; ++i) {
        const int ctrl = i, tgt = (i + 1) % 6;
        const int cm = 1 << (5 - ctrl), tm = 1 << (5 - tgt);
        float pr = __shfl_xor(ar, tm);
        float pi = __shfl_xor(ai, tm);
        bool take = (l & cm) != 0;
        ar = take ? pr : ar;
        ai = take ? pi : ai;
    }

    #pragma unroll
    for (int i = 0; i < 6; ++i) {
        const int mask = 1 << (5 - i);
        float th = 0.5f * qw[2 * 6 + i];
        float c = cosf(th), sn = sinf(th);
        float pr = __shfl_xor(ar, mask);
        float pi = __shfl_xor(ai, mask);
        float sg = (l & mask) ? sn : -sn;
        float nr = c * ar + sg * pr;
        float ni = c * ai + sg * pi;
        ar = nr; ai = ni;
        th = 0.5f * qw[3 * 6 + i];
        c = cosf(th); sn = sinf(th);
        float zn = (l & mask) ? 1.0f : -1.0f;
        nr = c * ar - zn * sn * ai;
        ni = c * ai + zn * sn * ar;
        ar = nr; ai = ni;
    }

    #pragma unroll
    for (int i = 0; i < 6; i += 2) {
        const int cm = 1 << (5 - i), tm = 1 << (5 - (i + 1));
        float pr = __shfl_xor(ar, tm);
        float pi = __shfl_xor(ai, tm);
        bool take = (l & cm) != 0;
        ar = take ? pr : ar;
        ai = take ? pi : ai;
    }

    #pragma unroll
    for (int i = 0; i < 6; ++i) {
        const int mask = 1 << (5 - i);
        float th = 0.5f * qw[4 * 6 + i];
        float c = cosf(th), sn = sinf(th);
        float pr = __shfl_xor(ar, mask);
        float pi = __shfl_xor(ai, mask);
        float nr = c * ar + sn * pi;
        float ni = c * ai - sn * pr;
        ar = nr; ai = ni;
    }

    Umat[(l * 64 + b) * 2 + 0] = ar;   // K-MAJOR: row k=l, col j=b
    Umat[(l * 64 + b) * 2 + 1] = ai;
}

// ---------------------------------------------------------------------------
// Front MLP tail (layers 2,3 + half-product tables). Verified since R3.
// ---------------------------------------------------------------------------
__device__ __forceinline__ void front_tail(
    const float h1[32],
    const float* __restrict__ W2, const float* __restrict__ b2,
    const float* __restrict__ W3, const float* __restrict__ b3,
    float lo[8], float hi[8])
{
    float h2[16];
    #pragma unroll
    for (int o = 0; o < 16; ++o) h2[o] = b2[o];
    #pragma unroll
    for (int j = 0; j < 32; ++j) {
        #pragma unroll
        for (int o = 0; o < 16; ++o) h2[o] = fmaf(h1[j], W2[j * 16 + o], h2[o]);
    }
    #pragma unroll
    for (int o = 0; o < 16; ++o) h2[o] = fmaxf(h2[o], 0.0f);

    float cq[6], sq[6];
    #pragma unroll
    for (int q = 0; q < 6; ++q) {
        float t = b3[q];
        #pragma unroll
        for (int j = 0; j < 16; ++j) t = fmaf(h2[j], W3[j * 6 + q], t);
        t = tanhf(t);
        t = fminf(1.0f, fmaxf(-1.0f, t));
        float half = t * (0.5f * PI_F);
        sq[q] = sinf(half);
        cq[q] = cosf(half);
    }

    {
        float f3[2] = {cq[3], sq[3]};
        float f4[2] = {cq[4], sq[4]};
        float f5[2] = {cq[5], sq[5]};
        #pragma unroll
        for (int m = 0; m < 8; ++m)
            lo[m] = f3[(m >> 2) & 1] * f4[(m >> 1) & 1] * f5[m & 1];
        float f0[2] = {cq[0], sq[0]};
        float f1[2] = {cq[1], sq[1]};
        float f2[2] = {cq[2], sq[2]};
        #pragma unroll
        for (int m = 0; m < 8; ++m)
            hi[m] = f0[(m >> 2) & 1] * f1[(m >> 1) & 1] * f2[m & 1];
    }
}

// ---------------------------------------------------------------------------
// Split kernel A: front MLP, coalesced LDS-staged x + NT streams (R15, ~60us)
// ---------------------------------------------------------------------------
__global__ __launch_bounds__(256) void front_kernel(
    const float* __restrict__ x,
    const float* __restrict__ W1, const float* __restrict__ b1,
    const float* __restrict__ W2, const float* __restrict__ b2,
    const float* __restrict__ W3, const float* __restrict__ b3,
    float* __restrict__ tab, int B)
{
    __shared__ float Ls[256 * 36];           // 36 KB

    const int tid = threadIdx.x;
    const long sbase = (long)blockIdx.x * 256;
    const int s = (int)(sbase + tid);

    const f32x4* xg = reinterpret_cast<const f32x4*>(x);

    float h1[32];
    #pragma unroll
    for (int o = 0; o < 32; ++o) h1[o] = b1[o];

    #pragma unroll 1
    for (int tile = 0; tile < 4; ++tile) {
        #pragma unroll
        for (int i = 0; i < 8; ++i) {
            const int flat = i * 256 + tid;
            const int row = flat >> 3;
            const int c4  = flat & 7;
            long srow = sbase + row;
            if (srow >= B) srow = B - 1;
            f32x4 v = __builtin_nontemporal_load(&xg[(size_t)srow * 32 + tile * 8 + c4]);
            *reinterpret_cast<f32x4*>(&Ls[row * 36 + c4 * 4]) = v;
        }
        __syncthreads();

        #pragma unroll
        for (int c4 = 0; c4 < 8; ++c4) {
            float4 xv = *reinterpret_cast<const float4*>(&Ls[tid * 36 + c4 * 4]);
            const float* w = W1 + (tile * 32 + c4 * 4) * 32;
            #pragma unroll
            for (int o = 0; o < 32; ++o) h1[o] = fmaf(xv.x, w[o], h1[o]);
            #pragma unroll
            for (int o = 0; o < 32; ++o) h1[o] = fmaf(xv.y, w[32 + o], h1[o]);
            #pragma unroll
            for (int o = 0; o < 32; ++o) h1[o] = fmaf(xv.z, w[64 + o], h1[o]);
            #pragma unroll
            for (int o = 0; o < 32; ++o) h1[o] = fmaf(xv.w, w[96 + o], h1[o]);
        }
        __syncthreads();
    }

    #pragma unroll
    for (int o = 0; o < 32; ++o) h1[o] = fmaxf(h1[o], 0.0f);

    float lo[8], hi[8];
    front_tail(h1, W2, b2, W3, b3, lo, hi);

    if (s < B) {
        #pragma unroll
        for (int i = 0; i < 8; ++i)
            __builtin_nontemporal_store(lo[i], &tab[(size_t)i * B + s]);
        #pragma unroll
        for (int i = 0; i < 8; ++i)
            __builtin_nontemporal_store(hi[i], &tab[(size_t)(8 + i) * B + s]);
    }
}

// uniform-lane readlane -> SGPR float
__device__ __forceinline__ float readlane_f(float v, int srclane) {
    return __int_as_float(__builtin_amdgcn_readlane(__float_as_int(v), srclane));
}

// ---------------------------------------------------------------------------
// Split kernel B: WAVE-COOPERATIVE gemv + back MLP. One wave per block owns
// 64 samples. Lane k holds U row k in 32 named f32x4 (128 VGPRs), loaded once
// and PINNED LIVE via asm volatile "+v" constraints -- the data dependency
// prevents the scheduler from sinking/rematerializing the loads into the
// t-loop (the failure mode of R4/R6/R7). The t-loop is then pure VALU:
// 16 v_readlane (tables -> SGPR) + 144 reg-only FMA + 18-op WHT butterfly
// per sample; zero memory operations. unroll 2 = two independent sample
// chains per wave for ILP.
// ---------------------------------------------------------------------------
__global__ __launch_bounds__(64) void gemv_kernel(
    const float* __restrict__ tab,
    const float* __restrict__ Umat,
    const float* __restrict__ W4, const float* __restrict__ b4,
    const float* __restrict__ W5, const float* __restrict__ b5,
    float* __restrict__ out, int B)
{
    const int lane = threadIdx.x;            // 0..63, one wave per block
    const long sbase = (long)blockIdx.x * 64;
    const int  s_my  = (int)(sbase + lane);
    const int  s_ld  = (s_my < B) ? s_my : (B - 1);

    // own sample's half-product tables (per-lane, coalesced, NT)
    float lo0 = __builtin_nontemporal_load(&tab[(size_t)0  * B + s_ld]);
    float lo1 = __builtin_nontemporal_load(&tab[(size_t)1  * B + s_ld]);
    float lo2 = __builtin_nontemporal_load(&tab[(size_t)2  * B + s_ld]);
    float lo3 = __builtin_nontemporal_load(&tab[(size_t)3  * B + s_ld]);
    float lo4 = __builtin_nontemporal_load(&tab[(size_t)4  * B + s_ld]);
    float lo5 = __builtin_nontemporal_load(&tab[(size_t)5  * B + s_ld]);
    float lo6 = __builtin_nontemporal_load(&tab[(size_t)6  * B + s_ld]);
    float lo7 = __builtin_nontemporal_load(&tab[(size_t)7  * B + s_ld]);
    float hi0 = __builtin_nontemporal_load(&tab[(size_t)8  * B + s_ld]);
    float hi1 = __builtin_nontemporal_load(&tab[(size_t)9  * B + s_ld]);
    float hi2 = __builtin_nontemporal_load(&tab[(size_t)10 * B + s_ld]);
    float hi3 = __builtin_nontemporal_load(&tab[(size_t)11 * B + s_ld]);
    float hi4 = __builtin_nontemporal_load(&tab[(size_t)12 * B + s_ld]);
    float hi5 = __builtin_nontemporal_load(&tab[(size_t)13 * B + s_ld]);
    float hi6 = __builtin_nontemporal_load(&tab[(size_t)14 * B + s_ld]);
    float hi7 = __builtin_nontemporal_load(&tab[(size_t)15 * B + s_ld]);

    // this lane's U row (output k = lane): 32 named f32x4 = 128 VGPRs
    const f32x4* urow = reinterpret_cast<const f32x4*>(Umat + lane * 128);
    #define LOAD_U(I) f32x4 R##I = urow[I];
    LOAD_U(0)  LOAD_U(1)  LOAD_U(2)  LOAD_U(3)
    LOAD_U(4)  LOAD_U(5)  LOAD_U(6)  LOAD_U(7)
    LOAD_U(8)  LOAD_U(9)  LOAD_U(10) LOAD_U(11)
    LOAD_U(12) LOAD_U(13) LOAD_U(14) LOAD_U(15)
    LOAD_U(16) LOAD_U(17) LOAD_U(18) LOAD_U(19)
    LOAD_U(20) LOAD_U(21) LOAD_U(22) LOAD_U(23)
    LOAD_U(24) LOAD_U(25) LOAD_U(26) LOAD_U(27)
    LOAD_U(28) LOAD_U(29) LOAD_U(30) LOAD_U(31)
    #undef LOAD_U

    // PIN the rows live in VGPRs: creates a data dependency the scheduler
    // cannot sink/rematerialize past (the R4/R6/R7 failure mode).
    asm volatile("" : "+v"(R0),  "+v"(R1),  "+v"(R2),  "+v"(R3),
                      "+v"(R4),  "+v"(R5),  "+v"(R6),  "+v"(R7));
    asm volatile("" : "+v"(R8),  "+v"(R9),  "+v"(R10), "+v"(R11),
                      "+v"(R12), "+v"(R13), "+v"(R14), "+v"(R15));
    asm volatile("" : "+v"(R16), "+v"(R17), "+v"(R18), "+v"(R19),
                      "+v"(R20), "+v"(R21), "+v"(R22), "+v"(R23));
    asm volatile("" : "+v"(R24), "+v"(R25), "+v"(R26), "+v"(R27),
                      "+v"(R28), "+v"(R29), "+v"(R30), "+v"(R31));

    float q0 = 0.f, q1 = 0.f, q2 = 0.f, q3 = 0.f, q4 = 0.f, q5 = 0.f;

    // one jh-group: 8 complex FMA into (tr,ti), folded by bh into (pr,pim)
    #define GEMV_STEP(A, Bq, C, D, BH)                                  \
        {                                                               \
            float tr = A.x * bl0, ti = A.y * bl0;                       \
            tr = fmaf(A.z,  bl1, tr); ti = fmaf(A.w,  bl1, ti);         \
            tr = fmaf(Bq.x, bl2, tr); ti = fmaf(Bq.y, bl2, ti);         \
            tr = fmaf(Bq.z, bl3, tr); ti = fmaf(Bq.w, bl3, ti);         \
            tr = fmaf(C.x,  bl4, tr); ti = fmaf(C.y,  bl4, ti);         \
            tr = fmaf(C.z,  bl5, tr); ti = fmaf(C.w,  bl5, ti);         \
            tr = fmaf(D.x,  bl6, tr); ti = fmaf(D.y,  bl6, ti);         \
            tr = fmaf(D.z,  bl7, tr); ti = fmaf(D.w,  bl7, ti);         \
            pr  = fmaf(BH, tr, pr);                                     \
            pim = fmaf(BH, ti, pim);                                    \
        }

    #pragma unroll 2
    for (int t = 0; t < 64; ++t) {
        float bl0 = readlane_f(lo0, t), bl1 = readlane_f(lo1, t);
        float bl2 = readlane_f(lo2, t), bl3 = readlane_f(lo3, t);
        float bl4 = readlane_f(lo4, t), bl5 = readlane_f(lo5, t);
        float bl6 = readlane_f(lo6, t), bl7 = readlane_f(lo7, t);
        float bh0 = readlane_f(hi0, t), bh1 = readlane_f(hi1, t);
        float bh2 = readlane_f(hi2, t), bh3 = readlane_f(hi3, t);
        float bh4 = readlane_f(hi4, t), bh5 = readlane_f(hi5, t);
        float bh6 = readlane_f(hi6, t), bh7 = readlane_f(hi7, t);

        float pr = 0.f, pim = 0.f;
        GEMV_STEP(R0,  R1,  R2,  R3,  bh0)
        GEMV_STEP(R4,  R5,  R6,  R7,  bh1)
        GEMV_STEP(R8,  R9,  R10, R11, bh2)
        GEMV_STEP(R12, R13, R14, R15, bh3)
        GEMV_STEP(R16, R17, R18, R19, bh4)
        GEMV_STEP(R20, R21, R22, R23, bh5)
        GEMV_STEP(R24, R25, R26, R27, bh6)
        GEMV_STEP(R28, R29, R30, R31, bh7)

        float p = fmaf(pr, pr, pim * pim);   // |phi_k|^2 at lane k

        // Walsh-Hadamard butterfly: lane r gets sum_k (-1)^{popc(r&k)} p_k
        float v = p;
        #pragma unroll
        for (int st = 0; st < 6; ++st) {
            const int m = 1 << st;
            float prt = __shfl_xor(v, m);
            v = (lane & m) ? (prt - v) : (prt + v);
        }

        // qv[q] = WHT coefficient at r = 1<<(5-q); deliver to owner lane t
        float g0 = readlane_f(v, 32);
        float g1 = readlane_f(v, 16);
        float g2 = readlane_f(v, 8);
        float g3 = readlane_f(v, 4);
        float g4 = readlane_f(v, 2);
        float g5 = readlane_f(v, 1);
        if (lane == t) { q0 = g0; q1 = g1; q2 = g2; q3 = g3; q4 = g4; q5 = g5; }
    }
    #undef GEMV_STEP

    if (s_my >= B) return;

    // ---- back MLP (per lane, own sample)
    float qv[6] = {q0, q1, q2, q3, q4, q5};
    float h4[16];
    #pragma unroll
    for (int o = 0; o < 16; ++o) h4[o] = b4[o];
    #pragma unroll
    for (int q = 0; q < 6; ++q) {
        #pragma unroll
        for (int o = 0; o < 16; ++o) h4[o] = fmaf(qv[q], W4[q * 16 + o], h4[o]);
    }
    #pragma unroll
    for (int o = 0; o < 16; ++o) h4[o] = fmaxf(h4[o], 0.0f);

    float o5[20];
    #pragma unroll
    for (int o = 0; o < 20; ++o) {
        float t = b5[o];
        #pragma unroll
        for (int j = 0; j < 16; ++j) t = fmaf(h4[j], W5[j * 20 + o], t);
        o5[o] = t;
    }

    f32x4* outv = reinterpret_cast<f32x4*>(out + (size_t)s_my * 20);
    #pragma unroll
    for (int i = 0; i < 5; ++i) {
        f32x4 v = {o5[4 * i], o5[4 * i + 1], o5[4 * i + 2], o5[4 * i + 3]};
        __builtin_nontemporal_store(v, &outv[i]);
    }
}

// ---------------------------------------------------------------------------
extern "C" void kernel_launch(void* const* d_in, const int* in_sizes, int n_in,
                              void* d_out, int out_size, void* d_ws, size_t ws_size,
                              hipStream_t stream) {
    const float* x  = (const float*)d_in[0];
    const float* W1 = (const float*)d_in[1];
    const float* b1 = (const float*)d_in[2];
    const float* W2 = (const float*)d_in[3];
    const float* b2 = (const float*)d_in[4];
    const float* W3 = (const float*)d_in[5];
    const float* b3 = (const float*)d_in[6];
    const float* qw = (const float*)d_in[7];
    const float* W4 = (const float*)d_in[8];
    const float* b4 = (const float*)d_in[9];
    const float* W5 = (const float*)d_in[10];
    const float* b5 = (const float*)d_in[11];
    float* out = (float*)d_out;

    const int B = in_sizes[0] / 128;

    float* Umat = (float*)d_ws;                       // 32 KB
    float* tab  = (float*)d_ws + 8192;                // 16 * B floats

    build_u<<<64, 64, 0, stream>>>(qw, Umat);
    front_kernel<<<(B + 255) / 256, 256, 0, stream>>>(
        x, W1, b1, W2, b2, W3, b3, tab, B);
    gemv_kernel<<<(B + 63) / 64, 64, 0, stream>>>(
        tab, Umat, W4, b4, W5, b5, out, B);
}

// Round 17
// 106.517 us; speedup vs baseline: 1.6237x; 1.6237x over previous
//
#include <hip/hip_runtime.h>
#include <hip/hip_bf16.h>
#include <math.h>

#define PI_F 3.14159265358979323846f

typedef float f32x4 __attribute__((ext_vector_type(4)));
typedef short bf16x8 __attribute__((ext_vector_type(8)));

__device__ __forceinline__ unsigned short bf_hi(float f) {
    return (unsigned short)(__float_as_uint(f) >> 16);     // truncate to bf16
}
__device__ __forceinline__ float from_bf(unsigned short h) {
    return __uint_as_float(((unsigned)h) << 16);
}

// ---------------------------------------------------------------------------
// Kernel 1: build the fixed 64x64 complex unitary U. K-MAJOR layout:
// Umat[k*128 + j*2 + {0,1}] = {Re,Im} of U[k][j].
// ---------------------------------------------------------------------------
__global__ __launch_bounds__(64) void build_u(const float* __restrict__ qw,
                                              float* __restrict__ Umat) {
    const int l = threadIdx.x;   // amplitude index k (0..63)
    const int b = blockIdx.x;    // input basis state j (0..63)

    float ar = (l == b) ? 1.0f : 0.0f;
    float ai = 0.0f;

    #pragma unroll
    for (int i = 0; i < 6; ++i) {
        const int mask = 1 << (5 - i);
        float th = 0.5f * qw[0 * 6 + i];
        float c = cosf(th), sn = sinf(th);
        float pr = __shfl_xor(ar, mask);
        float pi = __shfl_xor(ai, mask);
        float nr = c * ar + sn * pi;
        float ni = c * ai - sn * pr;
        ar = nr; ai = ni;
        th = 0.5f * qw[1 * 6 + i];
        c = cosf(th); sn = sinf(th);
        float zn = (l & mask) ? 1.0f : -1.0f;
        nr = c * ar - zn * sn * ai;
        ni = c * ai + zn * sn * ar;
        ar = nr; ai = ni;
    }

    #pragma unroll
    for (int i = 0; i < 6; ++i) {
        const int ctrl = i, tgt = (i + 1) % 6;
        const int cm = 1 << (5 - ctrl), tm = 1 << (5 - tgt);
        float pr = __shfl_xor(ar, tm);
        float pi = __shfl_xor(ai, tm);
        bool take = (l & cm) != 0;
        ar = take ? pr : ar;
        ai = take ? pi : ai;
    }

    #pragma unroll
    for (int i = 0; i < 6; ++i) {
        const int mask = 1 << (5 - i);
        float th = 0.5f * qw[2 * 6 + i];
        float c = cosf(th), sn = sinf(th);
        float pr = __shfl_xor(ar, mask);
        float pi = __shfl_xor(ai, mask);
        float sg = (l & mask) ? sn : -sn;
        float nr = c * ar + sg * pr;
        float ni = c * ai + sg * pi;
        ar = nr; ai = ni;
        th = 0.5f * qw[3 * 6 + i];
        c = cosf(th); sn = sinf(th);
        float zn = (l & mask) ? 1.0f : -1.0f;
        nr = c * ar - zn * sn * ai;
        ni = c * ai + zn * sn * ar;
        ar = nr; ai = ni;
    }

    #pragma unroll
    for (int i = 0; i < 6; i += 2) {
        const int cm = 1 << (5 - i), tm = 1 << (5 - (i + 1));
        float pr = __shfl_xor(ar, tm);
        float pi = __shfl_xor(ai, tm);
        bool take = (l & cm) != 0;
        ar = take ? pr : ar;
        ai = take ? pi : ai;
    }

    #pragma unroll
    for (int i = 0; i < 6; ++i) {
        const int mask = 1 << (5 - i);
        float th = 0.5f * qw[4 * 6 + i];
        float c = cosf(th), sn = sinf(th);
        float pr = __shfl_xor(ar, mask);
        float pi = __shfl_xor(ai, mask);
        float nr = c * ar + sn * pi;
        float ni = c * ai - sn * pr;
        ar = nr; ai = ni;
    }

    Umat[(l * 64 + b) * 2 + 0] = ar;   // k-major: row k=l, col j=b
    Umat[(l * 64 + b) * 2 + 1] = ai;
}

// ---------------------------------------------------------------------------
// Kernel 1b: pack U into MFMA B-fragment layout, split-bf16.
// Frag id f = vf*2 + part, vf = (ri*4 + t)*2 + h, part: 0=hi 1=lo.
// Lane l of frag f holds B[k'][n] with n = 16t + (l&15), k' = j = h*32 +
// (l>>4)*8 + e (e=0..7) -> one bf16x8 per (f, lane): Ubf[f*64 + l].
// ---------------------------------------------------------------------------
__global__ __launch_bounds__(64) void convert_u(const float* __restrict__ Umat,
                                                unsigned short* __restrict__ Ubf) {
    const int l = threadIdx.x;
    bf16x8* out8 = reinterpret_cast<bf16x8*>(Ubf);

    #pragma unroll
    for (int ri = 0; ri < 2; ++ri) {
        #pragma unroll
        for (int t = 0; t < 4; ++t) {
            #pragma unroll
            for (int h = 0; h < 2; ++h) {
                const int vf = (ri * 4 + t) * 2 + h;
                bf16x8 vh, vl;
                #pragma unroll
                for (int e = 0; e < 8; ++e) {
                    const int k = 16 * t + (l & 15);
                    const int j = h * 32 + (l >> 4) * 8 + e;
                    float v = Umat[k * 128 + j * 2 + ri];
                    unsigned short hh = bf_hi(v);
                    float rem = v - from_bf(hh);
                    unsigned short ll = bf_hi(rem);
                    vh[e] = (short)hh;
                    vl[e] = (short)ll;
                }
                out8[(vf * 2 + 0) * 64 + l] = vh;
                out8[(vf * 2 + 1) * 64 + l] = vl;
            }
        }
    }
}

// ---------------------------------------------------------------------------
// Front MLP tail (layers 2,3 + half-product tables). Verified since R3.
// ---------------------------------------------------------------------------
__device__ __forceinline__ void front_tail(
    const float h1[32],
    const float* __restrict__ W2, const float* __restrict__ b2,
    const float* __restrict__ W3, const float* __restrict__ b3,
    float lo[8], float hi[8])
{
    float h2[16];
    #pragma unroll
    for (int o = 0; o < 16; ++o) h2[o] = b2[o];
    #pragma unroll
    for (int j = 0; j < 32; ++j) {
        #pragma unroll
        for (int o = 0; o < 16; ++o) h2[o] = fmaf(h1[j], W2[j * 16 + o], h2[o]);
    }
    #pragma unroll
    for (int o = 0; o < 16; ++o) h2[o] = fmaxf(h2[o], 0.0f);

    float cq[6], sq[6];
    #pragma unroll
    for (int q = 0; q < 6; ++q) {
        float t = b3[q];
        #pragma unroll
        for (int j = 0; j < 16; ++j) t = fmaf(h2[j], W3[j * 6 + q], t);
        t = tanhf(t);
        t = fminf(1.0f, fmaxf(-1.0f, t));
        float half = t * (0.5f * PI_F);
        sq[q] = sinf(half);
        cq[q] = cosf(half);
    }

    {
        float f3[2] = {cq[3], sq[3]};
        float f4[2] = {cq[4], sq[4]};
        float f5[2] = {cq[5], sq[5]};
        #pragma unroll
        for (int m = 0; m < 8; ++m)
            lo[m] = f3[(m >> 2) & 1] * f4[(m >> 1) & 1] * f5[m & 1];
        float f0[2] = {cq[0], sq[0]};
        float f1[2] = {cq[1], sq[1]};
        float f2[2] = {cq[2], sq[2]};
        #pragma unroll
        for (int m = 0; m < 8; ++m)
            hi[m] = f0[(m >> 2) & 1] * f1[(m >> 1) & 1] * f2[m & 1];
    }
}

// ---------------------------------------------------------------------------
// Split kernel A: front MLP, coalesced LDS-staged x + NT streams (R15).
// ---------------------------------------------------------------------------
__global__ __launch_bounds__(256) void front_kernel(
    const float* __restrict__ x,
    const float* __restrict__ W1, const float* __restrict__ b1,
    const float* __restrict__ W2, const float* __restrict__ b2,
    const float* __restrict__ W3, const float* __restrict__ b3,
    float* __restrict__ tab, int B)
{
    __shared__ float Ls[256 * 36];           // 36 KB

    const int tid = threadIdx.x;
    const long sbase = (long)blockIdx.x * 256;
    const int s = (int)(sbase + tid);

    const f32x4* xg = reinterpret_cast<const f32x4*>(x);

    float h1[32];
    #pragma unroll
    for (int o = 0; o < 32; ++o) h1[o] = b1[o];

    #pragma unroll 1
    for (int tile = 0; tile < 4; ++tile) {
        #pragma unroll
        for (int i = 0; i < 8; ++i) {
            const int flat = i * 256 + tid;
            const int row = flat >> 3;
            const int c4  = flat & 7;
            long srow = sbase + row;
            if (srow >= B) srow = B - 1;
            f32x4 v = __builtin_nontemporal_load(&xg[(size_t)srow * 32 + tile * 8 + c4]);
            *reinterpret_cast<f32x4*>(&Ls[row * 36 + c4 * 4]) = v;
        }
        __syncthreads();

        #pragma unroll
        for (int c4 = 0; c4 < 8; ++c4) {
            float4 xv = *reinterpret_cast<const float4*>(&Ls[tid * 36 + c4 * 4]);
            const float* w = W1 + (tile * 32 + c4 * 4) * 32;
            #pragma unroll
            for (int o = 0; o < 32; ++o) h1[o] = fmaf(xv.x, w[o], h1[o]);
            #pragma unroll
            for (int o = 0; o < 32; ++o) h1[o] = fmaf(xv.y, w[32 + o], h1[o]);
            #pragma unroll
            for (int o = 0; o < 32; ++o) h1[o] = fmaf(xv.z, w[64 + o], h1[o]);
            #pragma unroll
            for (int o = 0; o < 32; ++o) h1[o] = fmaf(xv.w, w[96 + o], h1[o]);
        }
        __syncthreads();
    }

    #pragma unroll
    for (int o = 0; o < 32; ++o) h1[o] = fmaxf(h1[o], 0.0f);

    float lo[8], hi[8];
    front_tail(h1, W2, b2, W3, b3, lo, hi);

    if (s < B) {
        #pragma unroll
        for (int i = 0; i < 8; ++i)
            __builtin_nontemporal_store(lo[i], &tab[(size_t)i * B + s]);
        #pragma unroll
        for (int i = 0; i < 8; ++i)
            __builtin_nontemporal_store(hi[i], &tab[(size_t)(8 + i) * B + s]);
    }
}

// ---------------------------------------------------------------------------
// Split kernel B: MFMA GEMV + epilogue + back MLP.
// Block = 256 threads = 4 waves; wave wv owns samples sbase + wv*16 .. +15.
// Per wave: A-frags = split-bf16 psi (built in-register from tab), B-frags =
// pre-packed Ubf; 48 straight-line mfma_f32_16x16x32_bf16 (3 per (t,h) for
// split-bf16: AhBh + AlBh + AhBl). D layout (m89-verified): col=lane&15 =
// output k (mod 16), row=(lane>>4)*4+reg = sample. Epilogue: p = re^2+im^2;
// tile-sign sums over t (bits 5,4 of k) then 4-stage WHT butterfly within
// 16-lane groups (bits 3..0) -> 6 signed sums -> qlds -> back MLP on 64
// threads. NO LOOP around the MFMA working set => nothing to spill/sink.
// ---------------------------------------------------------------------------
__global__ __launch_bounds__(256) void gemv_mfma(
    const float* __restrict__ tab,
    const unsigned short* __restrict__ Ubf,
    const float* __restrict__ W4, const float* __restrict__ b4,
    const float* __restrict__ W5, const float* __restrict__ b5,
    float* __restrict__ out, int B)
{
    __shared__ float qlds[64][8];

    const int tid  = threadIdx.x;
    const int wv   = tid >> 6;
    const int lane = tid & 63;
    const int g    = lane >> 4;          // lane group (k-slice / row group)
    const int c    = lane & 15;          // column within tile / sample col
    const long blk = (long)blockIdx.x * 64;
    const int s    = (int)(blk + wv * 16 + c);       // this lane's A-row sample
    const int s_ld = (s < B) ? s : (B - 1);

    // ---- load this sample's half-product tables (16 floats)
    float tl[8], th[8];
    #pragma unroll
    for (int i = 0; i < 8; ++i)
        tl[i] = __builtin_nontemporal_load(&tab[(size_t)i * B + s_ld]);
    #pragma unroll
    for (int i = 0; i < 8; ++i)
        th[i] = __builtin_nontemporal_load(&tab[(size_t)(8 + i) * B + s_ld]);

    // hi-table entry for this lane's k'-slice (j>>3 = h*4 + g)
    float bh0 = (g == 0) ? th[0] : (g == 1) ? th[1] : (g == 2) ? th[2] : th[3];
    float bh1 = (g == 0) ? th[4] : (g == 1) ? th[5] : (g == 2) ? th[6] : th[7];

    // ---- A-frags: psi[s][j] split to bf16 hi/lo, j-slice per lane
    bf16x8 Ah0, Al0, Ah1, Al1;
    #pragma unroll
    for (int e = 0; e < 8; ++e) {
        float p0 = bh0 * tl[e];
        unsigned short h0 = bf_hi(p0);
        Ah0[e] = (short)h0;
        Al0[e] = (short)bf_hi(p0 - from_bf(h0));
        float p1 = bh1 * tl[e];
        unsigned short h1 = bf_hi(p1);
        Ah1[e] = (short)h1;
        Al1[e] = (short)bf_hi(p1 - from_bf(h1));
    }

    const bf16x8* Ub = reinterpret_cast<const bf16x8*>(Ubf);

    f32x4 accre[4], accim[4];
    #pragma unroll
    for (int t = 0; t < 4; ++t) { accre[t] = (f32x4)0.0f; accim[t] = (f32x4)0.0f; }

    // ---- 48 MFMAs, straight-line. f = ((ri*4+t)*2+h)*2+part.
    #pragma unroll
    for (int t = 0; t < 4; ++t) {
        bf16x8 B0h = Ub[(((0 * 4 + t) * 2 + 0) * 2 + 0) * 64 + lane];
        bf16x8 B0l = Ub[(((0 * 4 + t) * 2 + 0) * 2 + 1) * 64 + lane];
        bf16x8 B1h = Ub[(((0 * 4 + t) * 2 + 1) * 2 + 0) * 64 + lane];
        bf16x8 B1l = Ub[(((0 * 4 + t) * 2 + 1) * 2 + 1) * 64 + lane];
        accre[t] = __builtin_amdgcn_mfma_f32_16x16x32_bf16(Ah0, B0h, accre[t], 0, 0, 0);
        accre[t] = __builtin_amdgcn_mfma_f32_16x16x32_bf16(Al0, B0h, accre[t], 0, 0, 0);
        accre[t] = __builtin_amdgcn_mfma_f32_16x16x32_bf16(Ah0, B0l, accre[t], 0, 0, 0);
        accre[t] = __builtin_amdgcn_mfma_f32_16x16x32_bf16(Ah1, B1h, accre[t], 0, 0, 0);
        accre[t] = __builtin_amdgcn_mfma_f32_16x16x32_bf16(Al1, B1h, accre[t], 0, 0, 0);
        accre[t] = __builtin_amdgcn_mfma_f32_16x16x32_bf16(Ah1, B1l, accre[t], 0, 0, 0);
    }
    #pragma unroll
    for (int t = 0; t < 4; ++t) {
        bf16x8 B0h = Ub[(((1 * 4 + t) * 2 + 0) * 2 + 0) * 64 + lane];
        bf16x8 B0l = Ub[(((1 * 4 + t) * 2 + 0) * 2 + 1) * 64 + lane];
        bf16x8 B1h = Ub[(((1 * 4 + t) * 2 + 1) * 2 + 0) * 64 + lane];
        bf16x8 B1l = Ub[(((1 * 4 + t) * 2 + 1) * 2 + 1) * 64 + lane];
        accim[t] = __builtin_amdgcn_mfma_f32_16x16x32_bf16(Ah0, B0h, accim[t], 0, 0, 0);
        accim[t] = __builtin_amdgcn_mfma_f32_16x16x32_bf16(Al0, B0h, accim[t], 0, 0, 0);
        accim[t] = __builtin_amdgcn_mfma_f32_16x16x32_bf16(Ah0, B0l, accim[t], 0, 0, 0);
        accim[t] = __builtin_amdgcn_mfma_f32_16x16x32_bf16(Ah1, B1h, accim[t], 0, 0, 0);
        accim[t] = __builtin_amdgcn_mfma_f32_16x16x32_bf16(Al1, B1h, accim[t], 0, 0, 0);
        accim[t] = __builtin_amdgcn_mfma_f32_16x16x32_bf16(Ah1, B1l, accim[t], 0, 0, 0);
    }

    // ---- epilogue: probabilities + signed sums
    // p[t][r]: sample row = g*4+r, k = 16t + c.
    #pragma unroll
    for (int r = 0; r < 4; ++r) {
        float p0 = accre[0][r] * accre[0][r] + accim[0][r] * accim[0][r];
        float p1 = accre[1][r] * accre[1][r] + accim[1][r] * accim[1][r];
        float p2 = accre[2][r] * accre[2][r] + accim[2][r] * accim[2][r];
        float p3 = accre[3][r] * accre[3][r] + accim[3][r] * accim[3][r];

        float P0 = p0 + p1 + p2 + p3;        // for q2..q5 (t-signs +)
        float P1 = p0 + p1 - p2 - p3;        // q0: sign (-1)^{t>>1}  (k bit 5)
        float P2 = p0 - p1 + p2 - p3;        // q1: sign (-1)^{t&1}   (k bit 4)

        // WHT butterfly on P0 over c (low 4 bits of k)
        float v = P0;
        #pragma unroll
        for (int st = 0; st < 4; ++st) {
            const int m = 1 << st;
            float prt = __shfl_xor(v, m);
            v = (lane & m) ? (prt - v) : (prt + v);
        }
        // plain sums for P1, P2 over the 16-lane group
        #pragma unroll
        for (int st = 0; st < 4; ++st) P1 += __shfl_xor(P1, 1 << st);
        #pragma unroll
        for (int st = 0; st < 4; ++st) P2 += __shfl_xor(P2, 1 << st);

        const int sl = wv * 16 + g * 4 + r;
        if (c == 0) { qlds[sl][0] = P1; qlds[sl][1] = P2; }
        if (c == 8) qlds[sl][2] = v;
        if (c == 4) qlds[sl][3] = v;
        if (c == 2) qlds[sl][4] = v;
        if (c == 1) qlds[sl][5] = v;
    }

    __syncthreads();

    // ---- back MLP: one thread per sample (threads 0..63)
    if (tid < 64) {
        const int so = (int)(blk + tid);
        if (so < B) {
            float qv[6];
            #pragma unroll
            for (int i = 0; i < 6; ++i) qv[i] = qlds[tid][i];

            float h4[16];
            #pragma unroll
            for (int o = 0; o < 16; ++o) h4[o] = b4[o];
            #pragma unroll
            for (int q = 0; q < 6; ++q) {
                #pragma unroll
                for (int o = 0; o < 16; ++o) h4[o] = fmaf(qv[q], W4[q * 16 + o], h4[o]);
            }
            #pragma unroll
            for (int o = 0; o < 16; ++o) h4[o] = fmaxf(h4[o], 0.0f);

            float o5[20];
            #pragma unroll
            for (int o = 0; o < 20; ++o) {
                float t = b5[o];
                #pragma unroll
                for (int j = 0; j < 16; ++j) t = fmaf(h4[j], W5[j * 20 + o], t);
                o5[o] = t;
            }

            f32x4* outv = reinterpret_cast<f32x4*>(out + (size_t)so * 20);
            #pragma unroll
            for (int i = 0; i < 5; ++i) {
                f32x4 v = {o5[4 * i], o5[4 * i + 1], o5[4 * i + 2], o5[4 * i + 3]};
                __builtin_nontemporal_store(v, &outv[i]);
            }
        }
    }
}

// ---------------------------------------------------------------------------
extern "C" void kernel_launch(void* const* d_in, const int* in_sizes, int n_in,
                              void* d_out, int out_size, void* d_ws, size_t ws_size,
                              hipStream_t stream) {
    const float* x  = (const float*)d_in[0];
    const float* W1 = (const float*)d_in[1];
    const float* b1 = (const float*)d_in[2];
    const float* W2 = (const float*)d_in[3];
    const float* b2 = (const float*)d_in[4];
    const float* W3 = (const float*)d_in[5];
    const float* b3 = (const float*)d_in[6];
    const float* qw = (const float*)d_in[7];
    const float* W4 = (const float*)d_in[8];
    const float* b4 = (const float*)d_in[9];
    const float* W5 = (const float*)d_in[10];
    const float* b5 = (const float*)d_in[11];
    float* out = (float*)d_out;

    const int B = in_sizes[0] / 128;

    float* Umat = (float*)d_ws;                              // 8192 floats = 32 KB
    unsigned short* Ubf = (unsigned short*)((float*)d_ws + 8192);  // 16384 ushort = 32 KB
    float* tab  = (float*)d_ws + 16384;                      // 16*B floats

    build_u<<<64, 64, 0, stream>>>(qw, Umat);
    convert_u<<<1, 64, 0, stream>>>(Umat, Ubf);
    front_kernel<<<(B + 255) / 256, 256, 0, stream>>>(
        x, W1, b1, W2, b2, W3, b3, tab, B);
    gemv_mfma<<<(B + 63) / 64, 256, 0, stream>>>(
        tab, Ubf, W4, b4, W5, b5, out, B);
}

// Round 18
// 101.294 us; speedup vs baseline: 1.7074x; 1.0516x over previous
//
#include <hip/hip_runtime.h>
#include <hip/hip_bf16.h>
#include <math.h>

#define PI_F 3.14159265358979323846f

typedef float f32x4 __attribute__((ext_vector_type(4)));
typedef short bf16x8 __attribute__((ext_vector_type(8)));

__device__ __forceinline__ unsigned short bf_hi(float f) {
    return (unsigned short)(__float_as_uint(f) >> 16);     // truncate to bf16
}
__device__ __forceinline__ float from_bf(unsigned short h) {
    return __uint_as_float(((unsigned)h) << 16);
}

// ---------------------------------------------------------------------------
// Kernel 1: build the fixed 64x64 complex unitary U. K-MAJOR layout:
// Umat[k*128 + j*2 + {0,1}] = {Re,Im} of U[k][j].
// ---------------------------------------------------------------------------
__global__ __launch_bounds__(64) void build_u(const float* __restrict__ qw,
                                              float* __restrict__ Umat) {
    const int l = threadIdx.x;   // amplitude index k (0..63)
    const int b = blockIdx.x;    // input basis state j (0..63)

    float ar = (l == b) ? 1.0f : 0.0f;
    float ai = 0.0f;

    #pragma unroll
    for (int i = 0; i < 6; ++i) {
        const int mask = 1 << (5 - i);
        float th = 0.5f * qw[0 * 6 + i];
        float c = cosf(th), sn = sinf(th);
        float pr = __shfl_xor(ar, mask);
        float pi = __shfl_xor(ai, mask);
        float nr = c * ar + sn * pi;
        float ni = c * ai - sn * pr;
        ar = nr; ai = ni;
        th = 0.5f * qw[1 * 6 + i];
        c = cosf(th); sn = sinf(th);
        float zn = (l & mask) ? 1.0f : -1.0f;
        nr = c * ar - zn * sn * ai;
        ni = c * ai + zn * sn * ar;
        ar = nr; ai = ni;
    }

    #pragma unroll
    for (int i = 0; i < 6; ++i) {
        const int ctrl = i, tgt = (i + 1) % 6;
        const int cm = 1 << (5 - ctrl), tm = 1 << (5 - tgt);
        float pr = __shfl_xor(ar, tm);
        float pi = __shfl_xor(ai, tm);
        bool take = (l & cm) != 0;
        ar = take ? pr : ar;
        ai = take ? pi : ai;
    }

    #pragma unroll
    for (int i = 0; i < 6; ++i) {
        const int mask = 1 << (5 - i);
        float th = 0.5f * qw[2 * 6 + i];
        float c = cosf(th), sn = sinf(th);
        float pr = __shfl_xor(ar, mask);
        float pi = __shfl_xor(ai, mask);
        float sg = (l & mask) ? sn : -sn;
        float nr = c * ar + sg * pr;
        float ni = c * ai + sg * pi;
        ar = nr; ai = ni;
        th = 0.5f * qw[3 * 6 + i];
        c = cosf(th); sn = sinf(th);
        float zn = (l & mask) ? 1.0f : -1.0f;
        nr = c * ar - zn * sn * ai;
        ni = c * ai + zn * sn * ar;
        ar = nr; ai = ni;
    }

    #pragma unroll
    for (int i = 0; i < 6; i += 2) {
        const int cm = 1 << (5 - i), tm = 1 << (5 - (i + 1));
        float pr = __shfl_xor(ar, tm);
        float pi = __shfl_xor(ai, tm);
        bool take = (l & cm) != 0;
        ar = take ? pr : ar;
        ai = take ? pi : ai;
    }

    #pragma unroll
    for (int i = 0; i < 6; ++i) {
        const int mask = 1 << (5 - i);
        float th = 0.5f * qw[4 * 6 + i];
        float c = cosf(th), sn = sinf(th);
        float pr = __shfl_xor(ar, mask);
        float pi = __shfl_xor(ai, mask);
        float nr = c * ar + sn * pi;
        float ni = c * ai - sn * pr;
        ar = nr; ai = ni;
    }

    Umat[(l * 64 + b) * 2 + 0] = ar;   // k-major: row k=l, col j=b
    Umat[(l * 64 + b) * 2 + 1] = ai;
}

// ---------------------------------------------------------------------------
// Kernel 1b: pack U (B-frags for gemv, R17-verified) AND W1 (B-frags for the
// front L1 GEMM) into split-bf16 MFMA fragment layout.
// U:  f = ((ri*4+t)*2+h)*2+part ; lane l: B[k'=h*32+(l>>4)*8+e][n=16t+(l&15)]
// W1: f = (ks*2+nt)*2+part     ; lane l: W1[k=ks*32+(l>>4)*8+e][o=nt*16+(l&15)]
// ---------------------------------------------------------------------------
__global__ __launch_bounds__(64) void convert_all(
    const float* __restrict__ Umat, const float* __restrict__ W1,
    unsigned short* __restrict__ Ubf, unsigned short* __restrict__ W1bf)
{
    const int l = threadIdx.x;
    bf16x8* out8 = reinterpret_cast<bf16x8*>(Ubf);

    #pragma unroll
    for (int ri = 0; ri < 2; ++ri) {
        #pragma unroll
        for (int t = 0; t < 4; ++t) {
            #pragma unroll
            for (int h = 0; h < 2; ++h) {
                const int vf = (ri * 4 + t) * 2 + h;
                bf16x8 vh, vl;
                #pragma unroll
                for (int e = 0; e < 8; ++e) {
                    const int k = 16 * t + (l & 15);
                    const int j = h * 32 + (l >> 4) * 8 + e;
                    float v = Umat[k * 128 + j * 2 + ri];
                    unsigned short hh = bf_hi(v);
                    vh[e] = (short)hh;
                    vl[e] = (short)bf_hi(v - from_bf(hh));
                }
                out8[(vf * 2 + 0) * 64 + l] = vh;
                out8[(vf * 2 + 1) * 64 + l] = vl;
            }
        }
    }

    bf16x8* w8 = reinterpret_cast<bf16x8*>(W1bf);
    #pragma unroll
    for (int ks = 0; ks < 4; ++ks) {
        #pragma unroll
        for (int nt = 0; nt < 2; ++nt) {
            bf16x8 vh, vl;
            #pragma unroll
            for (int e = 0; e < 8; ++e) {
                float v = W1[(ks * 32 + (l >> 4) * 8 + e) * 32 + nt * 16 + (l & 15)];
                unsigned short hh = bf_hi(v);
                vh[e] = (short)hh;
                vl[e] = (short)bf_hi(v - from_bf(hh));
            }
            w8[((ks * 2 + nt) * 2 + 0) * 64 + l] = vh;
            w8[((ks * 2 + nt) * 2 + 1) * 64 + l] = vl;
        }
    }
}

// ---------------------------------------------------------------------------
// Front MLP tail (layers 2,3 + half-product tables). Verified since R3.
// ---------------------------------------------------------------------------
__device__ __forceinline__ void front_tail(
    const float h1[32],
    const float* __restrict__ W2, const float* __restrict__ b2,
    const float* __restrict__ W3, const float* __restrict__ b3,
    float lo[8], float hi[8])
{
    float h2[16];
    #pragma unroll
    for (int o = 0; o < 16; ++o) h2[o] = b2[o];
    #pragma unroll
    for (int j = 0; j < 32; ++j) {
        #pragma unroll
        for (int o = 0; o < 16; ++o) h2[o] = fmaf(h1[j], W2[j * 16 + o], h2[o]);
    }
    #pragma unroll
    for (int o = 0; o < 16; ++o) h2[o] = fmaxf(h2[o], 0.0f);

    float cq[6], sq[6];
    #pragma unroll
    for (int q = 0; q < 6; ++q) {
        float t = b3[q];
        #pragma unroll
        for (int j = 0; j < 16; ++j) t = fmaf(h2[j], W3[j * 6 + q], t);
        t = tanhf(t);
        t = fminf(1.0f, fmaxf(-1.0f, t));
        float half = t * (0.5f * PI_F);
        sq[q] = sinf(half);
        cq[q] = cosf(half);
    }

    {
        float f3[2] = {cq[3], sq[3]};
        float f4[2] = {cq[4], sq[4]};
        float f5[2] = {cq[5], sq[5]};
        #pragma unroll
        for (int m = 0; m < 8; ++m)
            lo[m] = f3[(m >> 2) & 1] * f4[(m >> 1) & 1] * f5[m & 1];
        float f0[2] = {cq[0], sq[0]};
        float f1[2] = {cq[1], sq[1]};
        float f2[2] = {cq[2], sq[2]};
        #pragma unroll
        for (int m = 0; m < 8; ++m)
            hi[m] = f0[(m >> 2) & 1] * f1[(m >> 1) & 1] * f2[m & 1];
    }
}

// ---------------------------------------------------------------------------
// Split kernel A (MFMA): front MLP. Block = 256 threads = 4 waves = 256
// samples. Wave wv computes 4 M-tiles of 16 samples: L1 (128->32) as 96
// straight-line split-bf16 MFMAs against pre-packed W1 frags. D -> LDS
// [256][33] (padded, conflict-free tail reads); tail = one sample/thread:
// +b1, relu, layers 2/3, tables -> NT stores to tab SoA planes.
// ---------------------------------------------------------------------------
__global__ __launch_bounds__(256) void front_mfma(
    const float* __restrict__ x,
    const unsigned short* __restrict__ W1bf, const float* __restrict__ b1,
    const float* __restrict__ W2, const float* __restrict__ b2,
    const float* __restrict__ W3, const float* __restrict__ b3,
    float* __restrict__ tab, int B)
{
    __shared__ float h1lds[256][33];

    const int tid  = threadIdx.x;
    const int wv   = tid >> 6;
    const int lane = tid & 63;
    const int g    = lane >> 4;
    const int c    = lane & 15;
    const long blk = (long)blockIdx.x * 256;

    const bf16x8* Wb = reinterpret_cast<const bf16x8*>(W1bf);

    #pragma unroll
    for (int mt = 0; mt < 4; ++mt) {
        long t0 = blk + wv * 64 + mt * 16 + c;
        const int srow = (int)((t0 < B) ? t0 : (B - 1));
        const float* xrow = x + (size_t)srow * 128;

        f32x4 acc0 = (f32x4)0.0f, acc1 = (f32x4)0.0f;

        #pragma unroll
        for (int ks = 0; ks < 4; ++ks) {
            f32x4 xa = __builtin_nontemporal_load(
                reinterpret_cast<const f32x4*>(xrow + ks * 32 + g * 8));
            f32x4 xb = __builtin_nontemporal_load(
                reinterpret_cast<const f32x4*>(xrow + ks * 32 + g * 8 + 4));
            bf16x8 Ah, Al;
            #pragma unroll
            for (int e = 0; e < 4; ++e) {
                unsigned short hh = bf_hi(xa[e]);
                Ah[e] = (short)hh;
                Al[e] = (short)bf_hi(xa[e] - from_bf(hh));
            }
            #pragma unroll
            for (int e = 0; e < 4; ++e) {
                unsigned short hh = bf_hi(xb[e]);
                Ah[4 + e] = (short)hh;
                Al[4 + e] = (short)bf_hi(xb[e] - from_bf(hh));
            }

            bf16x8 B0h = Wb[((ks * 2 + 0) * 2 + 0) * 64 + lane];
            bf16x8 B0l = Wb[((ks * 2 + 0) * 2 + 1) * 64 + lane];
            bf16x8 B1h = Wb[((ks * 2 + 1) * 2 + 0) * 64 + lane];
            bf16x8 B1l = Wb[((ks * 2 + 1) * 2 + 1) * 64 + lane];

            acc0 = __builtin_amdgcn_mfma_f32_16x16x32_bf16(Ah, B0h, acc0, 0, 0, 0);
            acc0 = __builtin_amdgcn_mfma_f32_16x16x32_bf16(Al, B0h, acc0, 0, 0, 0);
            acc0 = __builtin_amdgcn_mfma_f32_16x16x32_bf16(Ah, B0l, acc0, 0, 0, 0);
            acc1 = __builtin_amdgcn_mfma_f32_16x16x32_bf16(Ah, B1h, acc1, 0, 0, 0);
            acc1 = __builtin_amdgcn_mfma_f32_16x16x32_bf16(Al, B1h, acc1, 0, 0, 0);
            acc1 = __builtin_amdgcn_mfma_f32_16x16x32_bf16(Ah, B1l, acc1, 0, 0, 0);
        }

        // D: row = g*4 + r (sample within tile), col = c (+16 for ntile 1)
        #pragma unroll
        for (int r = 0; r < 4; ++r) {
            h1lds[wv * 64 + mt * 16 + g * 4 + r][c]      = acc0[r];
            h1lds[wv * 64 + mt * 16 + g * 4 + r][16 + c] = acc1[r];
        }
    }

    __syncthreads();

    // ---- tail: one sample per thread
    const int s = (int)(blk + tid);
    float h1[32];
    #pragma unroll
    for (int o = 0; o < 32; ++o) h1[o] = fmaxf(h1lds[tid][o] + b1[o], 0.0f);

    float lo[8], hi[8];
    front_tail(h1, W2, b2, W3, b3, lo, hi);

    if (s < B) {
        #pragma unroll
        for (int i = 0; i < 8; ++i)
            __builtin_nontemporal_store(lo[i], &tab[(size_t)i * B + s]);
        #pragma unroll
        for (int i = 0; i < 8; ++i)
            __builtin_nontemporal_store(hi[i], &tab[(size_t)(8 + i) * B + s]);
    }
}

// ---------------------------------------------------------------------------
// Split kernel B: MFMA GEMV + epilogue + back MLP (R17, verified).
// ---------------------------------------------------------------------------
__global__ __launch_bounds__(256) void gemv_mfma(
    const float* __restrict__ tab,
    const unsigned short* __restrict__ Ubf,
    const float* __restrict__ W4, const float* __restrict__ b4,
    const float* __restrict__ W5, const float* __restrict__ b5,
    float* __restrict__ out, int B)
{
    __shared__ float qlds[64][8];

    const int tid  = threadIdx.x;
    const int wv   = tid >> 6;
    const int lane = tid & 63;
    const int g    = lane >> 4;
    const int c    = lane & 15;
    const long blk = (long)blockIdx.x * 64;
    const int s    = (int)(blk + wv * 16 + c);
    const int s_ld = (s < B) ? s : (B - 1);

    float tl[8], th[8];
    #pragma unroll
    for (int i = 0; i < 8; ++i)
        tl[i] = __builtin_nontemporal_load(&tab[(size_t)i * B + s_ld]);
    #pragma unroll
    for (int i = 0; i < 8; ++i)
        th[i] = __builtin_nontemporal_load(&tab[(size_t)(8 + i) * B + s_ld]);

    float bh0 = (g == 0) ? th[0] : (g == 1) ? th[1] : (g == 2) ? th[2] : th[3];
    float bh1 = (g == 0) ? th[4] : (g == 1) ? th[5] : (g == 2) ? th[6] : th[7];

    bf16x8 Ah0, Al0, Ah1, Al1;
    #pragma unroll
    for (int e = 0; e < 8; ++e) {
        float p0 = bh0 * tl[e];
        unsigned short h0 = bf_hi(p0);
        Ah0[e] = (short)h0;
        Al0[e] = (short)bf_hi(p0 - from_bf(h0));
        float p1 = bh1 * tl[e];
        unsigned short h1 = bf_hi(p1);
        Ah1[e] = (short)h1;
        Al1[e] = (short)bf_hi(p1 - from_bf(h1));
    }

    const bf16x8* Ub = reinterpret_cast<const bf16x8*>(Ubf);

    f32x4 accre[4], accim[4];
    #pragma unroll
    for (int t = 0; t < 4; ++t) { accre[t] = (f32x4)0.0f; accim[t] = (f32x4)0.0f; }

    #pragma unroll
    for (int t = 0; t < 4; ++t) {
        bf16x8 B0h = Ub[(((0 * 4 + t) * 2 + 0) * 2 + 0) * 64 + lane];
        bf16x8 B0l = Ub[(((0 * 4 + t) * 2 + 0) * 2 + 1) * 64 + lane];
        bf16x8 B1h = Ub[(((0 * 4 + t) * 2 + 1) * 2 + 0) * 64 + lane];
        bf16x8 B1l = Ub[(((0 * 4 + t) * 2 + 1) * 2 + 1) * 64 + lane];
        accre[t] = __builtin_amdgcn_mfma_f32_16x16x32_bf16(Ah0, B0h, accre[t], 0, 0, 0);
        accre[t] = __builtin_amdgcn_mfma_f32_16x16x32_bf16(Al0, B0h, accre[t], 0, 0, 0);
        accre[t] = __builtin_amdgcn_mfma_f32_16x16x32_bf16(Ah0, B0l, accre[t], 0, 0, 0);
        accre[t] = __builtin_amdgcn_mfma_f32_16x16x32_bf16(Ah1, B1h, accre[t], 0, 0, 0);
        accre[t] = __builtin_amdgcn_mfma_f32_16x16x32_bf16(Al1, B1h, accre[t], 0, 0, 0);
        accre[t] = __builtin_amdgcn_mfma_f32_16x16x32_bf16(Ah1, B1l, accre[t], 0, 0, 0);
    }
    #pragma unroll
    for (int t = 0; t < 4; ++t) {
        bf16x8 B0h = Ub[(((1 * 4 + t) * 2 + 0) * 2 + 0) * 64 + lane];
        bf16x8 B0l = Ub[(((1 * 4 + t) * 2 + 0) * 2 + 1) * 64 + lane];
        bf16x8 B1h = Ub[(((1 * 4 + t) * 2 + 1) * 2 + 0) * 64 + lane];
        bf16x8 B1l = Ub[(((1 * 4 + t) * 2 + 1) * 2 + 1) * 64 + lane];
        accim[t] = __builtin_amdgcn_mfma_f32_16x16x32_bf16(Ah0, B0h, accim[t], 0, 0, 0);
        accim[t] = __builtin_amdgcn_mfma_f32_16x16x32_bf16(Al0, B0h, accim[t], 0, 0, 0);
        accim[t] = __builtin_amdgcn_mfma_f32_16x16x32_bf16(Ah0, B0l, accim[t], 0, 0, 0);
        accim[t] = __builtin_amdgcn_mfma_f32_16x16x32_bf16(Ah1, B1h, accim[t], 0, 0, 0);
        accim[t] = __builtin_amdgcn_mfma_f32_16x16x32_bf16(Al1, B1h, accim[t], 0, 0, 0);
        accim[t] = __builtin_amdgcn_mfma_f32_16x16x32_bf16(Ah1, B1l, accim[t], 0, 0, 0);
    }

    #pragma unroll
    for (int r = 0; r < 4; ++r) {
        float p0 = accre[0][r] * accre[0][r] + accim[0][r] * accim[0][r];
        float p1 = accre[1][r] * accre[1][r] + accim[1][r] * accim[1][r];
        float p2 = accre[2][r] * accre[2][r] + accim[2][r] * accim[2][r];
        float p3 = accre[3][r] * accre[3][r] + accim[3][r] * accim[3][r];

        float P0 = p0 + p1 + p2 + p3;
        float P1 = p0 + p1 - p2 - p3;
        float P2 = p0 - p1 + p2 - p3;

        float v = P0;
        #pragma unroll
        for (int st = 0; st < 4; ++st) {
            const int m = 1 << st;
            float prt = __shfl_xor(v, m);
            v = (lane & m) ? (prt - v) : (prt + v);
        }
        #pragma unroll
        for (int st = 0; st < 4; ++st) P1 += __shfl_xor(P1, 1 << st);
        #pragma unroll
        for (int st = 0; st < 4; ++st) P2 += __shfl_xor(P2, 1 << st);

        const int sl = wv * 16 + g * 4 + r;
        if (c == 0) { qlds[sl][0] = P1; qlds[sl][1] = P2; }
        if (c == 8) qlds[sl][2] = v;
        if (c == 4) qlds[sl][3] = v;
        if (c == 2) qlds[sl][4] = v;
        if (c == 1) qlds[sl][5] = v;
    }

    __syncthreads();

    if (tid < 64) {
        const int so = (int)(blk + tid);
        if (so < B) {
            float qv[6];
            #pragma unroll
            for (int i = 0; i < 6; ++i) qv[i] = qlds[tid][i];

            float h4[16];
            #pragma unroll
            for (int o = 0; o < 16; ++o) h4[o] = b4[o];
            #pragma unroll
            for (int q = 0; q < 6; ++q) {
                #pragma unroll
                for (int o = 0; o < 16; ++o) h4[o] = fmaf(qv[q], W4[q * 16 + o], h4[o]);
            }
            #pragma unroll
            for (int o = 0; o < 16; ++o) h4[o] = fmaxf(h4[o], 0.0f);

            float o5[20];
            #pragma unroll
            for (int o = 0; o < 20; ++o) {
                float t = b5[o];
                #pragma unroll
                for (int j = 0; j < 16; ++j) t = fmaf(h4[j], W5[j * 20 + o], t);
                o5[o] = t;
            }

            f32x4* outv = reinterpret_cast<f32x4*>(out + (size_t)so * 20);
            #pragma unroll
            for (int i = 0; i < 5; ++i) {
                f32x4 v = {o5[4 * i], o5[4 * i + 1], o5[4 * i + 2], o5[4 * i + 3]};
                __builtin_nontemporal_store(v, &outv[i]);
            }
        }
    }
}

// ---------------------------------------------------------------------------
extern "C" void kernel_launch(void* const* d_in, const int* in_sizes, int n_in,
                              void* d_out, int out_size, void* d_ws, size_t ws_size,
                              hipStream_t stream) {
    const float* x  = (const float*)d_in[0];
    const float* W1 = (const float*)d_in[1];
    const float* b1 = (const float*)d_in[2];
    const float* W2 = (const float*)d_in[3];
    const float* b2 = (const float*)d_in[4];
    const float* W3 = (const float*)d_in[5];
    const float* b3 = (const float*)d_in[6];
    const float* qw = (const float*)d_in[7];
    const float* W4 = (const float*)d_in[8];
    const float* b4 = (const float*)d_in[9];
    const float* W5 = (const float*)d_in[10];
    const float* b5 = (const float*)d_in[11];
    float* out = (float*)d_out;

    const int B = in_sizes[0] / 128;

    float* Umat = (float*)d_ws;                                   // 8192 floats
    unsigned short* Ubf  = (unsigned short*)((float*)d_ws + 8192);  // 16384 ushort
    unsigned short* W1bf = (unsigned short*)((float*)d_ws + 16384); // 8192 ushort
    float* tab  = (float*)d_ws + 20480;                           // 16*B floats

    build_u<<<64, 64, 0, stream>>>(qw, Umat);
    convert_all<<<1, 64, 0, stream>>>(Umat, W1, Ubf, W1bf);
    front_mfma<<<(B + 255) / 256, 256, 0, stream>>>(
        x, W1bf, b1, W2, b2, W3, b3, tab, B);
    gemv_mfma<<<(B + 63) / 64, 256, 0, stream>>>(
        tab, Ubf, W4, b4, W5, b5, out, B);
}